// Round 4
// baseline (185.907 us; speedup 1.0000x reference)
//
#include <hip/hip_runtime.h>
#include <hip/hip_bf16.h>

#define B_ 4
#define T_ 4096
#define C_ 1024
#define H_ 64

typedef __bf16 bf16x8 __attribute__((ext_vector_type(8)));
typedef float f32x4 __attribute__((ext_vector_type(4)));
typedef unsigned short u16x8 __attribute__((ext_vector_type(8)));

union Frag8 { uint4 u; bf16x8 b; u16x8 s; };

__device__ inline unsigned short bfbits(float f) {
  union { __hip_bfloat16 h; unsigned short u; } cv;
  cv.h = __float2bfloat16(f);
  return cv.u;
}

__device__ inline float b2f(unsigned u) {
  union { unsigned i; float f; } c; c.i = u << 16; return c.f;
}

__device__ inline bf16x8 ldb8(const unsigned short* p) {
  Frag8 f; f.u = *(const uint4*)p; return f.b;
}

// pack two fp32 -> (bf16(a)) | (bf16(b)<<16), round-half-up, 3 VALU ops
__device__ inline unsigned pkbf(float a, float b) {
  union { float f; unsigned u; } ua, ub; ua.f = a; ub.f = b;
  return __builtin_amdgcn_perm(ub.u + 0x8000u, ua.u + 0x8000u, 0x07060302u);
}

__device__ inline Frag8 packA(float4 a0, float4 a1) {
  Frag8 af;
  af.s[0] = bfbits(a0.x); af.s[1] = bfbits(a0.y);
  af.s[2] = bfbits(a0.z); af.s[3] = bfbits(a0.w);
  af.s[4] = bfbits(a1.x); af.s[5] = bfbits(a1.y);
  af.s[6] = bfbits(a1.z); af.s[7] = bfbits(a1.w);
  return af;
}

// async global->LDS, 16B per lane; LDS dest = wave-uniform base + lane*16
__device__ inline void gload16(const void* g, void* l) {
  __builtin_amdgcn_global_load_lds(
      (const __attribute__((address_space(1))) unsigned int*)g,
      (__attribute__((address_space(3))) unsigned int*)l, 16, 0, 0);
}

// ---------------- k0: convert W (3 x [64,1024] fp32) to bf16 ----------------
__global__ __launch_bounds__(256) void wconv(const float* __restrict__ Wq,
                                             const float* __restrict__ Wk,
                                             const float* __restrict__ Wv,
                                             unsigned short* __restrict__ Wb) {
  int i = blockIdx.x * 256 + threadIdx.x;
  size_t e = (size_t)i * 4;
  const float* src = (e < 65536) ? (Wq + e)
                   : (e < 131072 ? (Wk + (e - 65536)) : (Wv + (e - 131072)));
  float4 v = *(const float4*)src;
  unsigned long long o =
      (unsigned long long)bfbits(v.x)
    | ((unsigned long long)bfbits(v.y) << 16)
    | ((unsigned long long)bfbits(v.z) << 32)
    | ((unsigned long long)bfbits(v.w) << 48);
  *(unsigned long long*)(Wb + e) = o;
}

// ---------------- k1: QKV projection GEMM, 2-phase double-buffered ----------
__global__ __launch_bounds__(256) void qkv_proj(const float* __restrict__ x,
                                                const unsigned short* __restrict__ Wb,
                                                unsigned short* __restrict__ qkv,
                                                unsigned short* __restrict__ Vt) {
  __shared__ float xs[2][2048];               // 2 x (32 rows x 64 f32) = 16 KB
  __shared__ unsigned short Wsh[2][12288];    // 2 x (192 rows x 64 halves) = 48 KB
  const int lane = threadIdx.x & 63;
  const int wave = threadIdx.x >> 6;
  const int q16 = lane & 15, quad = lane >> 4;
  const int x7 = q16 & 7;
  const size_t row0 = (size_t)blockIdx.x * 32;

  const int sr = lane >> 4;                  // x-staging: row within group of 4
  const int sc_pos = lane & 15;              // x-staging: stored 16B-chunk pos
  const int rloc = lane >> 3;                // W-staging: row within group of 8
  const int cpos = lane & 7;                 // W-staging: stored 16B-chunk pos

  f32x4 acc[2][3] = {};

  auto stage = [&](int buf, int kc) {
#pragma unroll
    for (int ii = 0; ii < 2; ++ii) {
      int i = wave * 2 + ii;
      int r = i * 4 + sr;
      int sg = (sc_pos >> 1) ^ (r & 7);
      const float* gp = x + (row0 + r) * C_ + kc + sg * 8 + (sc_pos & 1) * 4;
      gload16(gp, &xs[buf][i * 256]);
    }
#pragma unroll
    for (int jj = 0; jj < 6; ++jj) {
      int j = wave * 6 + jj;
      int g = j * 8 + rloc;                  // flat col 0..191
      const unsigned short* gp = Wb + (size_t)(g >> 6) * 65536
                                    + (size_t)(g & 63) * C_ + kc + (cpos ^ rloc) * 8;
      gload16(gp, &Wsh[buf][j * 512]);
    }
  };

  stage(0, 0);
  __syncthreads();                           // prologue staging visible

  int cur = 0;
  for (int t = 0; t < 16; ++t) {
    if (t < 15) stage(cur ^ 1, (t + 1) * 64);  // prefetch next chunk
    const float* Xc = xs[cur];
    const unsigned short* Wc = Wsh[cur];
#pragma unroll
    for (int s = 0; s < 2; ++s) {
      bf16x8 bf[3];
#pragma unroll
      for (int ct = 0; ct < 3; ++ct) {
        int g = wave * 48 + ct * 16 + q16;
        bf[ct] = ldb8(&Wc[g * 64 + (((s * 4 + quad) ^ x7) * 8)]);
      }
#pragma unroll
      for (int rt = 0; rt < 2; ++rt) {
        int r = rt * 16 + q16;
        int p = ((s * 4 + quad) ^ (r & 7)) * 8;
        const float* ap = &Xc[r * 64 + p];
        float4 a0 = *(const float4*)ap;
        float4 a1 = *(const float4*)(ap + 4);
        Frag8 af = packA(a0, a1);
#pragma unroll
        for (int ct = 0; ct < 3; ++ct)
          acc[rt][ct] = __builtin_amdgcn_mfma_f32_16x16x32_bf16(
              af.b, bf[ct], acc[rt][ct], 0, 0, 0);
      }
    }
    __syncthreads();                         // readers done + next stage landed
    cur ^= 1;
  }

  const int bb = (int)(blockIdx.x >> 7);     // 128 blocks per batch
#pragma unroll
  for (int rt = 0; rt < 2; ++rt) {
    const int t0 = (int)(row0 - (size_t)bb * T_) + rt * 16 + quad * 4;
#pragma unroll
    for (int ct = 0; ct < 3; ++ct) {
      int gcol = wave * 48 + ct * 16;
      int mat = gcol >> 6, h = (gcol & 63) + q16;
      if (mat == 2) {                        // V: store transposed
        ushort4 v;
        v.x = bfbits(acc[rt][ct][0]); v.y = bfbits(acc[rt][ct][1]);
        v.z = bfbits(acc[rt][ct][2]); v.w = bfbits(acc[rt][ct][3]);
        *(ushort4*)(Vt + ((size_t)bb * H_ + h) * T_ + t0) = v;
      } else {
        // Q pre-scaled by (1/sqrt(64))*log2(e) -> softmax in exp2 domain
        float scale = (mat == 0) ? 0.18033688f : 1.0f;
#pragma unroll
        for (int r = 0; r < 4; ++r) {
          size_t row = row0 + rt * 16 + quad * 4 + r;
          qkv[(size_t)mat * 1048576 + row * H_ + h] = bfbits(acc[rt][ct][r] * scale);
        }
      }
    }
  }
}

// ---------------- k2: flash attention, QBLK=128, 2-phase dbuf K/V -----------
// grid (128, ny): x -> (b, qblk128 reversed), y = k-chunk of (1<<lgch) 64-row
// tiles. Block = 128 q-rows; wave w owns TWO 16-row fragments (rt=0,1) at
// rows qblk*128 + w*32 + rt*16. Both fragments share the staged K/V tile AND
// the ka/v LDS fragment reads (A/B operands), so staging+LDS+barrier cost per
// q-row is halved vs QBLK=64. Causal: lower fragments SKIP tiles beyond their
// limit (wave-uniform) instead of computing masked work; partial written iff
// cst*64 <= f0 (exactly the chunks merge reads). l accumulated per-lane,
// reduced once at the write (saves 2 shfl/tile/frag).
__global__ __launch_bounds__(256) void attn(const unsigned short* __restrict__ Q,
                                            const unsigned short* __restrict__ K,
                                            const unsigned short* __restrict__ Vt,
                                            float* __restrict__ part,
                                            int lgch, int nslots) {
  const int b = blockIdx.x >> 5;
  const int qblk = 31 - (blockIdx.x & 31);   // big triangles dispatch first
  const int ki_block = 2 * qblk + 2;         // 64-row k-tiles for top row
  const int c = blockIdx.y;
  const int cst = c << lgch;
  if (cst >= ki_block) return;
  const int tcnt = 1 << lgch;
  const int kend = (ki_block < cst + tcnt) ? ki_block : cst + tcnt;

  __shared__ unsigned short Ks[2][4096];     // 2 x (64 krows x 64 halves) = 16 KB
  __shared__ unsigned short Vs[2][4096];     // 2 x (64 hrows x 64 halves) = 16 KB
  const int lane = threadIdx.x & 63;
  const int wave = threadIdx.x >> 6;
  const int q16 = lane & 15, quad = lane >> 4;
  const int x7 = q16 & 7;
  const int rloc = lane >> 3, cpos = lane & 7;

  const unsigned short* Qb = Q + (size_t)b * T_ * H_;
  const unsigned short* Kb = K + (size_t)b * T_ * H_;
  const unsigned short* Vtb = Vt + (size_t)b * H_ * T_;

  auto stage = [&](int buf, int kt) {
    const int kkb = kt * 64;
#pragma unroll
    for (int ii = 0; ii < 2; ++ii) {
      int i = wave * 2 + ii;
      gload16(Kb + (size_t)(kkb + i * 8 + rloc) * H_ + (cpos ^ rloc) * 8,
              &Ks[buf][i * 512]);
      gload16(Vtb + (size_t)(i * 8 + rloc) * T_ + kkb + (cpos ^ rloc) * 8,
              &Vs[buf][i * 512]);
    }
  };

  const int q0w = qblk * 128 + wave * 32;    // this wave's first q-row
  int f0[2];  f0[0] = q0w;             f0[1] = q0w + 16;
  int kiF[2]; kiF[0] = (f0[0] >> 6) + 1; kiF[1] = (f0[1] >> 6) + 1;

  bf16x8 qf[2][2];
#pragma unroll
  for (int rt = 0; rt < 2; ++rt) {
    qf[rt][0] = ldb8(Qb + (size_t)(f0[rt] + q16) * H_ + quad * 8);
    qf[rt][1] = ldb8(Qb + (size_t)(f0[rt] + q16) * H_ + 32 + quad * 8);
  }

  f32x4 o[2][4] = {};
  float m[2] = {-3.0e38f, -3.0e38f}, l[2] = {0.0f, 0.0f};
  const int src0 = q16 + 32 * (quad & 1);
  const int kbsel = quad >> 1;

  stage(0, cst);
  __syncthreads();                           // prologue staging visible

  int cur = 0;
  for (int kt = cst; kt < kend; ++kt) {
    const int kkb = kt * 64;
    if (kt + 1 < kend) stage(cur ^ 1, kt + 1);  // prefetch next tile
    const unsigned short* Kc = Ks[cur];
    const unsigned short* Vc = Vs[cur];

    // ---- QK^T: S^T = K Q^T, ka fragments SHARED by both row-fragments ----
    f32x4 st[2][4];
#pragma unroll
    for (int kb = 0; kb < 4; ++kb) {
      bf16x8 ka0 = ldb8(&Kc[(kb * 16 + q16) * 64 + ((quad ^ x7) * 8)]);
      bf16x8 ka1 = ldb8(&Kc[(kb * 16 + q16) * 64 + (((quad + 4) ^ x7) * 8)]);
#pragma unroll
      for (int rt = 0; rt < 2; ++rt) {
        if (kt < kiF[rt]) {                  // wave-uniform causal skip
          f32x4 s = {0.f, 0.f, 0.f, 0.f};
          s = __builtin_amdgcn_mfma_f32_16x16x32_bf16(ka0, qf[rt][0], s, 0, 0, 0);
          s = __builtin_amdgcn_mfma_f32_16x16x32_bf16(ka1, qf[rt][1], s, 0, 0, 0);
          st[rt][kb] = s;
        }
      }
    }
#pragma unroll
    for (int rt = 0; rt < 2; ++rt) {
      if (kt == kiF[rt] - 1) {               // this fragment's diagonal tile
        const int qa = f0[rt] + q16;
#pragma unroll
        for (int kb = 0; kb < 4; ++kb)
#pragma unroll
          for (int r = 0; r < 4; ++r)
            if (kkb + kb * 16 + quad * 4 + r > qa) st[rt][kb][r] = -3.0e38f;
      }
    }

    // ---- online softmax (exp2 domain, defer-max, per-lane l partials) ----
    unsigned pk[2][4][2];
#pragma unroll
    for (int rt = 0; rt < 2; ++rt) {
      if (kt < kiF[rt]) {
        float mloc = fmaxf(fmaxf(st[rt][0][0], st[rt][0][1]),
                           fmaxf(st[rt][0][2], st[rt][0][3]));
#pragma unroll
        for (int kb = 1; kb < 4; ++kb)
          mloc = fmaxf(mloc, fmaxf(fmaxf(st[rt][kb][0], st[rt][kb][1]),
                                   fmaxf(st[rt][kb][2], st[rt][kb][3])));
        mloc = fmaxf(mloc, __shfl_xor(mloc, 16));
        mloc = fmaxf(mloc, __shfl_xor(mloc, 32));
        const bool defer = __all(mloc - m[rt] <= 8.0f);
        const float mnew = defer ? m[rt] : fmaxf(m[rt], mloc);
        float lsum = 0.f;
#pragma unroll
        for (int kb = 0; kb < 4; ++kb) {
          float p0 = exp2f(st[rt][kb][0] - mnew);
          float p1 = exp2f(st[rt][kb][1] - mnew);
          float p2 = exp2f(st[rt][kb][2] - mnew);
          float p3 = exp2f(st[rt][kb][3] - mnew);
          lsum += (p0 + p1) + (p2 + p3);
          pk[rt][kb][0] = pkbf(p0, p1);
          pk[rt][kb][1] = pkbf(p2, p3);
        }
        if (defer) {
          l[rt] += lsum;                     // alpha == 1, no rescale
        } else {
          float alpha = exp2f(m[rt] - mnew);
          l[rt] = l[rt] * alpha + lsum;
          m[rt] = mnew;
          float ar0 = __shfl(alpha, quad * 4 + 0);
          float ar1 = __shfl(alpha, quad * 4 + 1);
          float ar2 = __shfl(alpha, quad * 4 + 2);
          float ar3 = __shfl(alpha, quad * 4 + 3);
#pragma unroll
          for (int ct = 0; ct < 4; ++ct) {
            o[rt][ct][0] *= ar0; o[rt][ct][1] *= ar1;
            o[rt][ct][2] *= ar2; o[rt][ct][3] *= ar3;
          }
        }
      }
    }

    // ---- P^T -> A-layout + PV; v fragments SHARED by both row-fragments ---
#pragma unroll
    for (int kb2 = 0; kb2 < 2; ++kb2) {
      int vp = ((kb2 * 4 + quad) ^ x7) * 8;
      bf16x8 v0 = ldb8(&Vc[(q16 + 0)  * 64 + vp]);
      bf16x8 v1 = ldb8(&Vc[(q16 + 16) * 64 + vp]);
      bf16x8 v2 = ldb8(&Vc[(q16 + 32) * 64 + vp]);
      bf16x8 v3 = ldb8(&Vc[(q16 + 48) * 64 + vp]);
#pragma unroll
      for (int rt = 0; rt < 2; ++rt) {
        if (kt < kiF[rt]) {
          int xA = __shfl((int)pk[rt][2 * kb2][0], src0);
          int xB = __shfl((int)pk[rt][2 * kb2 + 1][0], src0);
          int yA = __shfl((int)pk[rt][2 * kb2][1], src0);
          int yB = __shfl((int)pk[rt][2 * kb2 + 1][1], src0);
          int zA = __shfl((int)pk[rt][2 * kb2][0], src0 + 16);
          int zB = __shfl((int)pk[rt][2 * kb2 + 1][0], src0 + 16);
          int wA = __shfl((int)pk[rt][2 * kb2][1], src0 + 16);
          int wB = __shfl((int)pk[rt][2 * kb2 + 1][1], src0 + 16);
          Frag8 pf;
          pf.u.x = (unsigned)(kbsel ? xB : xA);
          pf.u.y = (unsigned)(kbsel ? yB : yA);
          pf.u.z = (unsigned)(kbsel ? zB : zA);
          pf.u.w = (unsigned)(kbsel ? wB : wA);
          o[rt][0] = __builtin_amdgcn_mfma_f32_16x16x32_bf16(pf.b, v0, o[rt][0], 0, 0, 0);
          o[rt][1] = __builtin_amdgcn_mfma_f32_16x16x32_bf16(pf.b, v1, o[rt][1], 0, 0, 0);
          o[rt][2] = __builtin_amdgcn_mfma_f32_16x16x32_bf16(pf.b, v2, o[rt][2], 0, 0, 0);
          o[rt][3] = __builtin_amdgcn_mfma_f32_16x16x32_bf16(pf.b, v3, o[rt][3], 0, 0, 0);
        }
      }
    }
    __syncthreads();                         // readers done + next stage landed
    cur ^= 1;
  }

  // ---- per-fragment partial write (iff merge will read this chunk) ----
#pragma unroll
  for (int rt = 0; rt < 2; ++rt) {
    if ((cst << 6) <= f0[rt]) {
      const int qtl = f0[rt] >> 4;           // 16-row tile index, 0..255
      float lr = l[rt];
      lr += __shfl_xor(lr, 16);
      lr += __shfl_xor(lr, 32);
      float* Pf = part + ((size_t)((b << 8) + qtl) * nslots + c) * 544;
      unsigned* Pw = (unsigned*)Pf;
      Pw[0 * 64 + lane] = pkbf(o[rt][0][0], o[rt][0][1]);
      Pw[1 * 64 + lane] = pkbf(o[rt][0][2], o[rt][0][3]);
      Pw[2 * 64 + lane] = pkbf(o[rt][1][0], o[rt][1][1]);
      Pw[3 * 64 + lane] = pkbf(o[rt][1][2], o[rt][1][3]);
      Pw[4 * 64 + lane] = pkbf(o[rt][2][0], o[rt][2][1]);
      Pw[5 * 64 + lane] = pkbf(o[rt][2][2], o[rt][2][3]);
      Pw[6 * 64 + lane] = pkbf(o[rt][3][0], o[rt][3][1]);
      Pw[7 * 64 + lane] = pkbf(o[rt][3][2], o[rt][3][3]);
      if (quad == 0) { Pf[512 + q16] = m[rt]; Pf[528 + q16] = lr; }
    }
  }
}

// ---------------- k3: merge partials per q-tile, normalize, store ----------
__global__ __launch_bounds__(256) void attn_merge(const float* __restrict__ part,
                                                  float* __restrict__ out,
                                                  int lgch, int nslots) {
  const int qt = blockIdx.x;                 // 0..1023
  const int qtl = qt & 255, b = qt >> 8;
  const int ki = (qtl >> 2) + 1;             // 64-row k-tiles
  const int nch = (ki + (1 << lgch) - 1) >> lgch;
  const int t = threadIdx.x;
  const int row = t >> 4, col0 = (t & 15) * 4;
  const int i = (col0 >> 4) * 4 + (row & 3); // packed index (fixed over 4 cols)
  const int lane0 = (row >> 2) * 16 + (col0 & 15);
  const int sh = 16 * (i & 1);
  const float* P0 = part + (size_t)qt * nslots * 544;
  float M = -3.0e38f;
  for (int c2 = 0; c2 < nch; ++c2) M = fmaxf(M, P0[c2 * 544 + 512 + row]);
  float L = 0.f;
  float ax = 0.f, ay = 0.f, az = 0.f, aw = 0.f;
  for (int c2 = 0; c2 < nch; ++c2) {
    const float* P = P0 + c2 * 544;
    float w = exp2f(P[512 + row] - M);
    L += w * P[528 + row];
    const unsigned* Pw = (const unsigned*)P;
    uint4 wd = *(const uint4*)&Pw[(i >> 1) * 64 + lane0];
    ax += w * b2f((wd.x >> sh) & 0xffffu);
    ay += w * b2f((wd.y >> sh) & 0xffffu);
    az += w * b2f((wd.z >> sh) & 0xffffu);
    aw += w * b2f((wd.w >> sh) & 0xffffu);
  }
  float inv = 1.0f / L;
  float4 r = {ax * inv, ay * inv, az * inv, aw * inv};
  *(float4*)(out + ((size_t)b * T_ + qtl * 16 + row) * H_ + col0) = r;
}

extern "C" void kernel_launch(void* const* d_in, const int* in_sizes, int n_in,
                              void* d_out, int out_size, void* d_ws, size_t ws_size,
                              hipStream_t stream) {
  const float* x  = (const float*)d_in[0];
  const float* Wq = (const float*)d_in[1];
  const float* Wk = (const float*)d_in[2];
  const float* Wv = (const float*)d_in[3];
  float* out = (float*)d_out;
  unsigned short* ws = (unsigned short*)d_ws;

  // ws layout (ushort units):
  //   [0, 196608)           Wb  (Q|K|V bf16 weights)
  //   [196608, +2*1048576)  Q,K bf16 [B*T][64]  (Q pre-scaled, exp2 domain)
  //   next 1048576          Vt bf16 [B][64][T]
  //   next (float region)   partials: 1024 * nslots * 544 fp32 words
  unsigned short* Wb  = ws;
  unsigned short* qkv = ws + 196608;
  unsigned short* Vt  = qkv + (size_t)2 * 1048576;
  float* part = (float*)(ws + 196608 + (size_t)3 * 1048576);

  // chunk = 4 tiles (16 y-chunks, 35.7 MB partials) if workspace allows,
  // else the proven chunk = 8 layout (17.8 MB partials).
  const size_t base_bytes = ((size_t)196608 + (size_t)3 * 1048576) * 2;
  const size_t need16 = base_bytes + (size_t)1024 * 16 * 544 * 4;
  int lgch = 3, ny = 8, nslots = 8;
  if (ws_size >= need16) { lgch = 2; ny = 16; nslots = 16; }

  wconv<<<192, 256, 0, stream>>>(Wq, Wk, Wv, Wb);
  qkv_proj<<<512, 256, 0, stream>>>(x, Wb, qkv, Vt);
  attn<<<dim3(128, ny), 256, 0, stream>>>(qkv, qkv + 1048576, Vt, part, lgch, nslots);
  attn_merge<<<1024, 256, 0, stream>>>(part, out, lgch, nslots);
}

// Round 5
// 161.849 us; speedup vs baseline: 1.1486x; 1.1486x over previous
//
#include <hip/hip_runtime.h>
#include <hip/hip_bf16.h>

#define B_ 4
#define T_ 4096
#define C_ 1024
#define H_ 64

typedef __bf16 bf16x8 __attribute__((ext_vector_type(8)));
typedef float f32x4 __attribute__((ext_vector_type(4)));
typedef unsigned short u16x8 __attribute__((ext_vector_type(8)));

union Frag8 { uint4 u; bf16x8 b; u16x8 s; };

__device__ inline unsigned short bfbits(float f) {
  union { __hip_bfloat16 h; unsigned short u; } cv;
  cv.h = __float2bfloat16(f);
  return cv.u;
}

__device__ inline float b2f(unsigned u) {
  union { unsigned i; float f; } c; c.i = u << 16; return c.f;
}

__device__ inline bf16x8 ldb8(const unsigned short* p) {
  Frag8 f; f.u = *(const uint4*)p; return f.b;
}

// pack two fp32 -> (bf16(a)) | (bf16(b)<<16), round-half-up, 3 VALU ops
__device__ inline unsigned pkbf(float a, float b) {
  union { float f; unsigned u; } ua, ub; ua.f = a; ub.f = b;
  return __builtin_amdgcn_perm(ub.u + 0x8000u, ua.u + 0x8000u, 0x07060302u);
}

__device__ inline Frag8 packA(float4 a0, float4 a1) {
  Frag8 af;
  af.s[0] = bfbits(a0.x); af.s[1] = bfbits(a0.y);
  af.s[2] = bfbits(a0.z); af.s[3] = bfbits(a0.w);
  af.s[4] = bfbits(a1.x); af.s[5] = bfbits(a1.y);
  af.s[6] = bfbits(a1.z); af.s[7] = bfbits(a1.w);
  return af;
}

// async global->LDS, 16B per lane; LDS dest = wave-uniform base + lane*16
__device__ inline void gload16(const void* g, void* l) {
  __builtin_amdgcn_global_load_lds(
      (const __attribute__((address_space(1))) unsigned int*)g,
      (__attribute__((address_space(3))) unsigned int*)l, 16, 0, 0);
}

// ---------------- k0: convert W (3 x [64,1024] fp32) to bf16 ----------------
__global__ __launch_bounds__(256) void wconv(const float* __restrict__ Wq,
                                             const float* __restrict__ Wk,
                                             const float* __restrict__ Wv,
                                             unsigned short* __restrict__ Wb) {
  int i = blockIdx.x * 256 + threadIdx.x;
  size_t e = (size_t)i * 4;
  const float* src = (e < 65536) ? (Wq + e)
                   : (e < 131072 ? (Wk + (e - 65536)) : (Wv + (e - 131072)));
  float4 v = *(const float4*)src;
  unsigned long long o =
      (unsigned long long)bfbits(v.x)
    | ((unsigned long long)bfbits(v.y) << 16)
    | ((unsigned long long)bfbits(v.z) << 32)
    | ((unsigned long long)bfbits(v.w) << 48);
  *(unsigned long long*)(Wb + e) = o;
}

// ---------------- k1: QKV projection GEMM, 2-phase double-buffered ----------
__global__ __launch_bounds__(256) void qkv_proj(const float* __restrict__ x,
                                                const unsigned short* __restrict__ Wb,
                                                unsigned short* __restrict__ qkv,
                                                unsigned short* __restrict__ Vt) {
  __shared__ float xs[2][2048];               // 2 x (32 rows x 64 f32) = 16 KB
  __shared__ unsigned short Wsh[2][12288];    // 2 x (192 rows x 64 halves) = 48 KB
  const int lane = threadIdx.x & 63;
  const int wave = threadIdx.x >> 6;
  const int q16 = lane & 15, quad = lane >> 4;
  const int x7 = q16 & 7;
  const size_t row0 = (size_t)blockIdx.x * 32;

  const int sr = lane >> 4;                  // x-staging: row within group of 4
  const int sc_pos = lane & 15;              // x-staging: stored 16B-chunk pos
  const int rloc = lane >> 3;                // W-staging: row within group of 8
  const int cpos = lane & 7;                 // W-staging: stored 16B-chunk pos

  f32x4 acc[2][3] = {};

  auto stage = [&](int buf, int kc) {
#pragma unroll
    for (int ii = 0; ii < 2; ++ii) {
      int i = wave * 2 + ii;
      int r = i * 4 + sr;
      int sg = (sc_pos >> 1) ^ (r & 7);
      const float* gp = x + (row0 + r) * C_ + kc + sg * 8 + (sc_pos & 1) * 4;
      gload16(gp, &xs[buf][i * 256]);
    }
#pragma unroll
    for (int jj = 0; jj < 6; ++jj) {
      int j = wave * 6 + jj;
      int g = j * 8 + rloc;                  // flat col 0..191
      const unsigned short* gp = Wb + (size_t)(g >> 6) * 65536
                                    + (size_t)(g & 63) * C_ + kc + (cpos ^ rloc) * 8;
      gload16(gp, &Wsh[buf][j * 512]);
    }
  };

  stage(0, 0);
  __syncthreads();                           // prologue staging visible

  int cur = 0;
  for (int t = 0; t < 16; ++t) {
    if (t < 15) stage(cur ^ 1, (t + 1) * 64);  // prefetch next chunk
    const float* Xc = xs[cur];
    const unsigned short* Wc = Wsh[cur];
#pragma unroll
    for (int s = 0; s < 2; ++s) {
      bf16x8 bf[3];
#pragma unroll
      for (int ct = 0; ct < 3; ++ct) {
        int g = wave * 48 + ct * 16 + q16;
        bf[ct] = ldb8(&Wc[g * 64 + (((s * 4 + quad) ^ x7) * 8)]);
      }
#pragma unroll
      for (int rt = 0; rt < 2; ++rt) {
        int r = rt * 16 + q16;
        int p = ((s * 4 + quad) ^ (r & 7)) * 8;
        const float* ap = &Xc[r * 64 + p];
        float4 a0 = *(const float4*)ap;
        float4 a1 = *(const float4*)(ap + 4);
        Frag8 af = packA(a0, a1);
#pragma unroll
        for (int ct = 0; ct < 3; ++ct)
          acc[rt][ct] = __builtin_amdgcn_mfma_f32_16x16x32_bf16(
              af.b, bf[ct], acc[rt][ct], 0, 0, 0);
      }
    }
    __syncthreads();                         // readers done + next stage landed
    cur ^= 1;
  }

  const int bb = (int)(blockIdx.x >> 7);     // 128 blocks per batch
#pragma unroll
  for (int rt = 0; rt < 2; ++rt) {
    const int t0 = (int)(row0 - (size_t)bb * T_) + rt * 16 + quad * 4;
#pragma unroll
    for (int ct = 0; ct < 3; ++ct) {
      int gcol = wave * 48 + ct * 16;
      int mat = gcol >> 6, h = (gcol & 63) + q16;
      if (mat == 2) {                        // V: store transposed
        ushort4 v;
        v.x = bfbits(acc[rt][ct][0]); v.y = bfbits(acc[rt][ct][1]);
        v.z = bfbits(acc[rt][ct][2]); v.w = bfbits(acc[rt][ct][3]);
        *(ushort4*)(Vt + ((size_t)bb * H_ + h) * T_ + t0) = v;
      } else {
        // Q pre-scaled by (1/sqrt(64))*log2(e) -> softmax in exp2 domain
        float scale = (mat == 0) ? 0.18033688f : 1.0f;
#pragma unroll
        for (int r = 0; r < 4; ++r) {
          size_t row = row0 + rt * 16 + quad * 4 + r;
          qkv[(size_t)mat * 1048576 + row * H_ + h] = bfbits(acc[rt][ct][r] * scale);
        }
      }
    }
  }
}

// ---------------- k2: flash attention, O^T formulation, zero-shuffle PV -----
// grid (256, ny): x -> (b, qblk reversed), y = k-chunk of (1<<lgch) 64-row
// tiles. QBLK=64 (wave owns 16 q-rows). Key trick: K rows are staged into LDS
// slots via permutation psi (applied to the GLOBAL source address; LDS dest
// linear, read pattern/banks unchanged), so after S^T = K.Q^T each lane's
// st/pk values are EXACTLY the B-operand fragment of P^T for O^T = V^T.P^T.
//   - P-transpose shuffles (16/tile) -> 0
//   - alpha broadcasts (4/rescale)   -> 0 (O^T C-layout: col=q16, per-lane alpha)
//   - lsum reduce (2/tile)           -> once per block (per-lane l partials)
// Defer-max (T13) kept. Partials: O^T bf16-pair-packed, (ct*64+lane)*2+p.
__global__ __launch_bounds__(256) void attn(const unsigned short* __restrict__ Q,
                                            const unsigned short* __restrict__ K,
                                            const unsigned short* __restrict__ Vt,
                                            float* __restrict__ part,
                                            int lgch, int nslots) {
  const int b = blockIdx.x >> 6;
  const int qblk = 63 - (blockIdx.x & 63);   // big triangles dispatch first
  const int ki = qblk + 1;                   // total 64-row k-tiles
  const int c = blockIdx.y;
  const int cst = c << lgch;
  if (cst >= ki) return;
  const int tcnt = 1 << lgch;
  const int kend = (ki < cst + tcnt) ? ki : cst + tcnt;

  __shared__ unsigned short Ks[2][4096];     // 2 x (64 slots x 64 halves) = 16 KB
  __shared__ unsigned short Vs[2][4096];     // 2 x (64 hrows x 64 halves) = 16 KB
  const int lane = threadIdx.x & 63;
  const int wave = threadIdx.x >> 6;
  const int q16 = lane & 15, quad = lane >> 4;
  const int x7 = q16 & 7;
  const int rloc = lane >> 3, cpos = lane & 7;

  const unsigned short* Qb = Q + (size_t)b * T_ * H_;
  const unsigned short* Kb = K + (size_t)b * T_ * H_;
  const unsigned short* Vtb = Vt + (size_t)b * H_ * T_;

  // K slot-row permutation: slot g holds K-row psi(g) of the tile.
  // psi(g) = 8*((g&15)>>2) + (g&3) + 4*((g>>4)&1) + 32*(g>>5)  (bijective)
  // => after QK^T, lane(q16,quad) holds P[q=q16][k = 8*quad+4*(kb&1)+32*(kb>>1)+r]
  //    which is exactly the P^T B-fragment (no cross-lane exchange needed).
  int psi_[2];
#pragma unroll
  for (int ii = 0; ii < 2; ++ii) {
    int g = (wave * 2 + ii) * 8 + rloc;
    psi_[ii] = 8 * ((g & 15) >> 2) + (g & 3) + 4 * ((g >> 4) & 1) + 32 * (g >> 5);
  }

  auto stage = [&](int buf, int kt) {
    const int kkb = kt * 64;
#pragma unroll
    for (int ii = 0; ii < 2; ++ii) {
      int i = wave * 2 + ii;
      gload16(Kb + (size_t)(kkb + psi_[ii]) * H_ + (cpos ^ rloc) * 8,
              &Ks[buf][i * 512]);
      gload16(Vtb + (size_t)(i * 8 + rloc) * T_ + kkb + (cpos ^ rloc) * 8,
              &Vs[buf][i * 512]);
    }
  };

  const int q0w = qblk * 64 + wave * 16;     // this wave's q-rows
  bf16x8 qf0 = ldb8(Qb + (size_t)(q0w + q16) * H_ + quad * 8);
  bf16x8 qf1 = ldb8(Qb + (size_t)(q0w + q16) * H_ + 32 + quad * 8);

  f32x4 o[4] = {};                           // O^T frag: h=ct*16+quad*4+r, q=q16
  float m = -3.0e38f, l = 0.0f;              // l = per-lane partial (this quad)
  const int q_abs = q0w + q16;

  stage(0, cst);
  __syncthreads();                           // prologue staging visible

  int cur = 0;
  for (int kt = cst; kt < kend; ++kt) {
    const int kkb = kt * 64;
    if (kt + 1 < kend) stage(cur ^ 1, kt + 1);  // prefetch next tile
    const unsigned short* Kc = Ks[cur];
    const unsigned short* Vc = Vs[cur];

    // ---- QK^T: S^T = K Q^T (A rows = permuted K rows; reads as before) ----
    f32x4 st[4];
#pragma unroll
    for (int kb = 0; kb < 4; ++kb) {
      bf16x8 ka0 = ldb8(&Kc[(kb * 16 + q16) * 64 + ((quad ^ x7) * 8)]);
      bf16x8 ka1 = ldb8(&Kc[(kb * 16 + q16) * 64 + (((quad + 4) ^ x7) * 8)]);
      f32x4 s = {0.f, 0.f, 0.f, 0.f};
      s = __builtin_amdgcn_mfma_f32_16x16x32_bf16(ka0, qf0, s, 0, 0, 0);
      s = __builtin_amdgcn_mfma_f32_16x16x32_bf16(ka1, qf1, s, 0, 0, 0);
      st[kb] = s;
    }
    if (kt == ki - 1) {                      // diagonal tile: causal mask
      const int kb8q = kkb + 8 * quad;       // st[kb][r] <-> k = kb8q + 4(kb&1)+32(kb>>1)+r
#pragma unroll
      for (int kb = 0; kb < 4; ++kb) {
        const int kof = kb8q + 4 * (kb & 1) + 32 * (kb >> 1);
#pragma unroll
        for (int r = 0; r < 4; ++r)
          if (kof + r > q_abs) st[kb][r] = -3.0e38f;
      }
    }

    // ---- online softmax (exp2 domain, defer-max, per-lane l partials) ----
    float mloc = fmaxf(fmaxf(st[0][0], st[0][1]), fmaxf(st[0][2], st[0][3]));
#pragma unroll
    for (int kb = 1; kb < 4; ++kb)
      mloc = fmaxf(mloc, fmaxf(fmaxf(st[kb][0], st[kb][1]), fmaxf(st[kb][2], st[kb][3])));
    mloc = fmaxf(mloc, __shfl_xor(mloc, 16));
    mloc = fmaxf(mloc, __shfl_xor(mloc, 32));
    const bool defer = __all(mloc - m <= 8.0f);   // wave-uniform
    const float mnew = defer ? m : fmaxf(m, mloc);
    float lsum = 0.f;
    unsigned pk[4][2];
#pragma unroll
    for (int kb = 0; kb < 4; ++kb) {
      float p0 = exp2f(st[kb][0] - mnew);
      float p1 = exp2f(st[kb][1] - mnew);
      float p2 = exp2f(st[kb][2] - mnew);
      float p3 = exp2f(st[kb][3] - mnew);
      lsum += (p0 + p1) + (p2 + p3);
      pk[kb][0] = pkbf(p0, p1);
      pk[kb][1] = pkbf(p2, p3);
    }
    if (defer) {
      l += lsum;                             // alpha == 1, no rescale
    } else {
      float alpha = exp2f(m - mnew);         // per-lane (col=q16 layout!)
      l = l * alpha + lsum;
      m = mnew;
#pragma unroll
      for (int ct = 0; ct < 4; ++ct) {
        o[ct][0] *= alpha; o[ct][1] *= alpha;
        o[ct][2] *= alpha; o[ct][3] *= alpha;
      }
    }

    // ---- PV: O^T += V^T P^T; P^T B-frag is lane-local (zero shuffles) ----
#pragma unroll
    for (int ks = 0; ks < 2; ++ks) {
      Frag8 pf;
      pf.u.x = pk[2 * ks][0];
      pf.u.y = pk[2 * ks][1];
      pf.u.z = pk[2 * ks + 1][0];
      pf.u.w = pk[2 * ks + 1][1];
      int vp = ((ks * 4 + quad) ^ x7) * 8;
      bf16x8 v0 = ldb8(&Vc[(q16 + 0)  * 64 + vp]);
      bf16x8 v1 = ldb8(&Vc[(q16 + 16) * 64 + vp]);
      bf16x8 v2 = ldb8(&Vc[(q16 + 32) * 64 + vp]);
      bf16x8 v3 = ldb8(&Vc[(q16 + 48) * 64 + vp]);
      o[0] = __builtin_amdgcn_mfma_f32_16x16x32_bf16(v0, pf.b, o[0], 0, 0, 0);
      o[1] = __builtin_amdgcn_mfma_f32_16x16x32_bf16(v1, pf.b, o[1], 0, 0, 0);
      o[2] = __builtin_amdgcn_mfma_f32_16x16x32_bf16(v2, pf.b, o[2], 0, 0, 0);
      o[3] = __builtin_amdgcn_mfma_f32_16x16x32_bf16(v3, pf.b, o[3], 0, 0, 0);
    }
    __syncthreads();                         // readers done + next stage landed
    cur ^= 1;
  }

  // ---- partial write: O^T pairs; word (ct*64+lane)*2+p packs h=..2p,2p+1 ----
  const int qtl = qblk * 4 + wave;
  float lr = l;
  lr += __shfl_xor(lr, 16);
  lr += __shfl_xor(lr, 32);
  float* Pf = part + ((size_t)((b << 8) + qtl) * nslots + c) * 544;
  unsigned* Pw = (unsigned*)Pf;
#pragma unroll
  for (int ct = 0; ct < 4; ++ct) {
    uint2 w;
    w.x = pkbf(o[ct][0], o[ct][1]);
    w.y = pkbf(o[ct][2], o[ct][3]);
    *(uint2*)&Pw[(ct * 64 + lane) * 2] = w;
  }
  if (quad == 0) { Pf[512 + q16] = m; Pf[528 + q16] = lr; }
}

// ---------------- k3: merge partials per q-tile, normalize, store ----------
// Partial O^T layout: word (ct*64 + quad*16 + q)*2 + p = bf16 pair
// (h = ct*16+quad*4+2p, h+1), col q. Thread -> (q=row, h=col0..col0+3).
__global__ __launch_bounds__(256) void attn_merge(const float* __restrict__ part,
                                                  float* __restrict__ out,
                                                  int lgch, int nslots) {
  const int qt = blockIdx.x;                 // 0..1023
  const int qtl = qt & 255, b = qt >> 8;
  const int ki = (qtl >> 2) + 1;             // 64-row k-tiles
  const int nch = (ki + (1 << lgch) - 1) >> lgch;
  const int t = threadIdx.x;
  const int row = t >> 4;                    // q 0..15
  const int col0 = (t & 15) * 4;             // h base
  const int ct = col0 >> 4;
  const int quad_s = (col0 >> 2) & 3;
  const int lane0 = quad_s * 16 + row;
  const float* P0 = part + (size_t)qt * nslots * 544;
  float M = -3.0e38f;
  for (int c2 = 0; c2 < nch; ++c2) M = fmaxf(M, P0[c2 * 544 + 512 + row]);
  float L = 0.f;
  float ax = 0.f, ay = 0.f, az = 0.f, aw = 0.f;
  for (int c2 = 0; c2 < nch; ++c2) {
    const float* P = P0 + c2 * 544;
    float wgt = exp2f(P[512 + row] - M);
    L += wgt * P[528 + row];
    const unsigned* Pww = (const unsigned*)P;
    uint2 wd = *(const uint2*)&Pww[(ct * 64 + lane0) * 2];
    ax += wgt * b2f(wd.x & 0xffffu);
    ay += wgt * b2f(wd.x >> 16);
    az += wgt * b2f(wd.y & 0xffffu);
    aw += wgt * b2f(wd.y >> 16);
  }
  float inv = 1.0f / L;
  float4 r = {ax * inv, ay * inv, az * inv, aw * inv};
  *(float4*)(out + ((size_t)b * T_ + qtl * 16 + row) * H_ + col0) = r;
}

extern "C" void kernel_launch(void* const* d_in, const int* in_sizes, int n_in,
                              void* d_out, int out_size, void* d_ws, size_t ws_size,
                              hipStream_t stream) {
  const float* x  = (const float*)d_in[0];
  const float* Wq = (const float*)d_in[1];
  const float* Wk = (const float*)d_in[2];
  const float* Wv = (const float*)d_in[3];
  float* out = (float*)d_out;
  unsigned short* ws = (unsigned short*)d_ws;

  // ws layout (ushort units):
  //   [0, 196608)           Wb  (Q|K|V bf16 weights)
  //   [196608, +2*1048576)  Q,K bf16 [B*T][64]  (Q pre-scaled, exp2 domain)
  //   next 1048576          Vt bf16 [B][64][T]
  //   next (float region)   partials: 1024 * nslots * 544 fp32 words
  unsigned short* Wb  = ws;
  unsigned short* qkv = ws + 196608;
  unsigned short* Vt  = qkv + (size_t)2 * 1048576;
  float* part = (float*)(ws + 196608 + (size_t)3 * 1048576);

  // chunk = 4 tiles (16 y-chunks, 35.7 MB partials) if workspace allows,
  // else the chunk = 8 layout (17.8 MB partials).
  const size_t base_bytes = ((size_t)196608 + (size_t)3 * 1048576) * 2;
  const size_t need16 = base_bytes + (size_t)1024 * 16 * 544 * 4;
  int lgch = 3, ny = 8, nslots = 8;
  if (ws_size >= need16) { lgch = 2; ny = 16; nslots = 16; }

  wconv<<<192, 256, 0, stream>>>(Wq, Wk, Wv, Wb);
  qkv_proj<<<512, 256, 0, stream>>>(x, Wb, qkv, Vt);
  attn<<<dim3(256, ny), 256, 0, stream>>>(qkv, qkv + 1048576, Vt, part, lgch, nslots);
  attn_merge<<<1024, 256, 0, stream>>>(part, out, lgch, nslots);
}